// Round 1
// baseline (251.593 us; speedup 1.0000x reference)
//
#include <hip/hip_runtime.h>

// Rotation of (32,3,512,512) fp32 by 15 degrees, bilinear, border=0.
// dst(y,x) = bilinear_src( a*(x-c) - b*(y-c) + c,  b*(x-c) + a*(y-c) + c )
// with a=cos(15deg), b=sin(15deg), c=256.

#define IMG_H 512
#define IMG_W 512
#define NPLANES 96   // B*C = 32*3

__constant__ const float kCosA = 0.96592582628906831f;  // cos(15 deg)
__constant__ const float kSinA = 0.25881904510252074f;  // sin(15 deg)

__global__ __launch_bounds__(256) void rot_kernel(const float* __restrict__ in,
                                                  float* __restrict__ out) {
    const int tid = blockIdx.x * blockDim.x + threadIdx.x;
    // Each thread produces 4 consecutive output pixels (one float4).
    // tid layout: [plane(96)][y(512)][x4(128)]
    const int x4   = (tid & (IMG_W / 4 - 1)) << 2;   // 0..508 step 4
    const int rest = tid >> 7;                        // / (W/4)
    const int y    = rest & (IMG_H - 1);
    const int bc   = rest >> 9;                       // / H

    const float* __restrict__ src = in + (size_t)bc * (IMG_H * IMG_W);

    const float fy  = (float)y - 256.0f;
    const float bxs = -kSinA * fy + 256.0f;  // xs = cos*fx + bxs
    const float bys =  kCosA * fy + 256.0f;  // ys = sin*fx + bys

    float o[4];
#pragma unroll
    for (int k = 0; k < 4; ++k) {
        const float fx = (float)(x4 + k) - 256.0f;
        const float xs = kCosA * fx + bxs;
        const float ys = kSinA * fx + bys;

        const float x0f = floorf(xs);
        const float y0f = floorf(ys);
        const float wx = xs - x0f;
        const float wy = ys - y0f;

        const int x0 = (int)x0f;
        const int y0 = (int)y0f;
        const int x1 = x0 + 1;
        const int y1 = y0 + 1;

        // validity masks (border constant 0)
        const float vx0 = ((unsigned)x0 < IMG_W) ? 1.0f : 0.0f;
        const float vx1 = ((unsigned)x1 < IMG_W) ? 1.0f : 0.0f;
        const float vy0 = ((unsigned)y0 < IMG_H) ? 1.0f : 0.0f;
        const float vy1 = ((unsigned)y1 < IMG_H) ? 1.0f : 0.0f;

        const float w00 = (1.0f - wy) * (1.0f - wx) * vy0 * vx0;
        const float w01 = (1.0f - wy) * wx          * vy0 * vx1;
        const float w10 = wy * (1.0f - wx)          * vy1 * vx0;
        const float w11 = wy * wx                   * vy1 * vx1;

        // clamped indices (always in-bounds loads; weight carries the mask)
        const int x0c = min(max(x0, 0), IMG_W - 1);
        const int x1c = min(max(x1, 0), IMG_W - 1);
        const int y0c = min(max(y0, 0), IMG_H - 1);
        const int y1c = min(max(y1, 0), IMG_H - 1);

        const float* __restrict__ r0 = src + y0c * IMG_W;
        const float* __restrict__ r1 = src + y1c * IMG_W;

        const float v00 = r0[x0c];
        const float v01 = r0[x1c];
        const float v10 = r1[x0c];
        const float v11 = r1[x1c];

        o[k] = v00 * w00 + v01 * w01 + v10 * w10 + v11 * w11;
    }

    float4 ov = make_float4(o[0], o[1], o[2], o[3]);
    reinterpret_cast<float4*>(out)[tid] = ov;
}

extern "C" void kernel_launch(void* const* d_in, const int* in_sizes, int n_in,
                              void* d_out, int out_size, void* d_ws, size_t ws_size,
                              hipStream_t stream) {
    const float* in = (const float*)d_in[0];
    float* out = (float*)d_out;

    // total float4 groups = 96*512*512/4 = 6,291,456 -> 24576 blocks of 256
    const int total4 = NPLANES * IMG_H * IMG_W / 4;
    const int block = 256;
    const int grid = total4 / block;
    rot_kernel<<<grid, block, 0, stream>>>(in, out);
}

// Round 2
// 216.112 us; speedup vs baseline: 1.1642x; 1.1642x over previous
//
#include <hip/hip_runtime.h>

// Rotation of (32,3,512,512) fp32 by 15 degrees, bilinear, border=0.
// LDS-tiled: each 256-thread block computes a 64x64 output tile, staging the
// rotated 80x80 source footprint in LDS (coalesced global reads), then does
// the bilinear taps as LDS gathers (bank-granular, no cache-line serialization).

#define IMG_H 512
#define IMG_W 512
#define NPLANES 96   // B*C
#define TS 64        // output tile edge
#define LROWS 80     // footprint rows  (63*(cos+sin)+margin = 79 -> 80)
#define LCOLS 80     // footprint cols
#define LSTRIDE 84   // LDS row stride in floats (16B-aligned, bank-decorrelated)

__global__ __launch_bounds__(256) void rot_kernel(const float* __restrict__ in,
                                                  float* __restrict__ out) {
    const float a = 0.96592582628906831f;  // cos(15 deg)
    const float b = 0.25881904510252074f;  // sin(15 deg)

    __shared__ float tile[LROWS * LSTRIDE];

    const int blk = blockIdx.x;
    const int tx = blk & 7;            // 8 tiles across
    const int ty = (blk >> 3) & 7;     // 8 tiles down
    const int bc = blk >> 6;           // plane index 0..95
    const int X0 = tx * TS;
    const int Y0 = ty * TS;

    const float* __restrict__ src = in + (size_t)bc * (IMG_H * IMG_W);

    // Footprint bounds. Same arithmetic shape as the compute phase below:
    //   xs = a*fx + bxs,  bxs = -b*fy + 256
    //   ys = b*fx + bys,  bys =  a*fy + 256
    // Monotonicity of fp rounding guarantees per-pixel xs/ys stay within
    // [floor(min), floor(max)+1], i.e. LDS indices land in [0, 79].
    const float fx_lo = (float)X0 - 256.0f;
    const float fy_lo = (float)Y0 - 256.0f;
    const float fy_hi = (float)(Y0 + 63) - 256.0f;

    const float xs_min = a * fx_lo + (-b * fy_hi + 256.0f);
    const float ys_min = b * fx_lo + ( a * fy_lo + 256.0f);
    const int xs0 = (int)floorf(xs_min);
    const int ys0 = (int)floorf(ys_min);

    const int t = threadIdx.x;

    // ---- Stage 80x80 source footprint into LDS (border-clamped: every cell
    //      holds a finite real pixel; zero-weight taps mask out-of-image ones).
    //      6400 cells / 256 threads = 25 iterations, coalesced dword runs.
#pragma unroll
    for (int it = 0; it < (LROWS * LCOLS) / 256; ++it) {
        const int idx = t + it * 256;
        const int r = idx / LCOLS;
        const int c = idx - r * LCOLS;
        const int gy = min(max(ys0 + r, 0), IMG_H - 1);
        const int gx = min(max(xs0 + c, 0), IMG_W - 1);
        tile[r * LSTRIDE + c] = src[gy * IMG_W + gx];
    }
    __syncthreads();

    // ---- Compute: each thread does 4 passes of 4 consecutive pixels.
    //      Thread t -> col4 = (t&15)*4, rows (t>>4) + 16*rr.
    const int col4 = (t & 15) << 2;
    const int row_base = t >> 4;
    float* __restrict__ dst = out + (size_t)bc * (IMG_H * IMG_W);

#pragma unroll
    for (int rr = 0; rr < 4; ++rr) {
        const int y = Y0 + row_base + (rr << 4);
        const float fy = (float)y - 256.0f;
        const float bxs = -b * fy + 256.0f;
        const float bys =  a * fy + 256.0f;

        float o[4];
#pragma unroll
        for (int k = 0; k < 4; ++k) {
            const int x = X0 + col4 + k;
            const float fx = (float)x - 256.0f;
            const float xs = a * fx + bxs;
            const float ys = b * fx + bys;

            const float x0f = floorf(xs);
            const float y0f = floorf(ys);
            const float wx = xs - x0f;
            const float wy = ys - y0f;
            const int x0 = (int)x0f;
            const int y0 = (int)y0f;

            // validity from GLOBAL coords (border constant 0)
            const float vx0 = ((unsigned)x0       < IMG_W) ? 1.0f : 0.0f;
            const float vx1 = ((unsigned)(x0 + 1) < IMG_W) ? 1.0f : 0.0f;
            const float vy0 = ((unsigned)y0       < IMG_H) ? 1.0f : 0.0f;
            const float vy1 = ((unsigned)(y0 + 1) < IMG_H) ? 1.0f : 0.0f;

            const float w00 = (1.0f - wy) * (1.0f - wx) * vy0 * vx0;
            const float w01 = (1.0f - wy) * wx          * vy0 * vx1;
            const float w10 = wy * (1.0f - wx)          * vy1 * vx0;
            const float w11 = wy * wx                   * vy1 * vx1;

            // LDS indices are in-bounds by footprint construction
            const int lr = y0 - ys0;
            const int lc = x0 - xs0;
            const float* __restrict__ p = &tile[lr * LSTRIDE + lc];
            const float v00 = p[0];
            const float v01 = p[1];
            const float v10 = p[LSTRIDE];
            const float v11 = p[LSTRIDE + 1];

            o[k] = v00 * w00 + v01 * w01 + v10 * w10 + v11 * w11;
        }
        *reinterpret_cast<float4*>(&dst[y * IMG_W + X0 + col4]) =
            make_float4(o[0], o[1], o[2], o[3]);
    }
}

extern "C" void kernel_launch(void* const* d_in, const int* in_sizes, int n_in,
                              void* d_out, int out_size, void* d_ws, size_t ws_size,
                              hipStream_t stream) {
    const float* in = (const float*)d_in[0];
    float* out = (float*)d_out;

    // 96 planes * 8x8 tiles = 6144 blocks
    const int grid = NPLANES * (IMG_H / TS) * (IMG_W / TS);
    rot_kernel<<<grid, 256, 0, stream>>>(in, out);
}

// Round 3
// 174.839 us; speedup vs baseline: 1.4390x; 1.2361x over previous
//
#include <hip/hip_runtime.h>

// Rotation of (32,3,512,512) fp32 by 15 degrees, bilinear, border=0.
// LDS-tiled, async-staged: each 256-thread block computes a 64x64 output tile.
// The rotated source footprint (80 rows x 84 cols, 16B-aligned origin) is
// staged with global_load_lds width=16 (direct HBM->LDS, no VGPR round-trip),
// then bilinear taps read from LDS. Out-of-image footprint cells are loaded
// from a buffer-clamped address (finite garbage) and masked exactly to zero
// by the validity weights, matching the reference's  vals * (w * valid).

#define IMG_H 512
#define IMG_W 512
#define NPLANES 96            // B*C
#define TS 64                 // output tile edge
#define LROWS 80              // footprint rows (63*(cos+sin)+2 margin)
#define LCOLS 84              // footprint cols incl. 16B-alignment slop (stride)
#define NGROUPS 1792          // 7 * 256 16B-groups (>= ceil(80*84/4)=1680, padded)
#define LDS_FLOATS (NGROUPS * 4)   // 7168 floats = 28672 B

typedef __attribute__((address_space(1))) const float gfloat;
typedef __attribute__((address_space(3))) float sfloat;

template <bool MASKED>
__device__ __forceinline__ void compute_tile(const float* __restrict__ tile,
                                             float* __restrict__ dst,
                                             int X0, int Y0, int xs0a, int ys0,
                                             int t, float a, float b) {
    const int col4 = (t & 15) << 2;
    const int row_base = t >> 4;
#pragma unroll
    for (int rr = 0; rr < 4; ++rr) {
        const int y = Y0 + row_base + (rr << 4);
        const float fy = (float)y - 256.0f;
        const float bxs = -b * fy + 256.0f;
        const float bys =  a * fy + 256.0f;

        float o[4];
#pragma unroll
        for (int k = 0; k < 4; ++k) {
            const int x = X0 + col4 + k;
            const float fx = (float)x - 256.0f;
            const float xs = a * fx + bxs;
            const float ys = b * fx + bys;

            const float x0f = floorf(xs);
            const float y0f = floorf(ys);
            const float wx = xs - x0f;
            const float wy = ys - y0f;
            const int x0 = (int)x0f;
            const int y0 = (int)y0f;

            float w00 = (1.0f - wy) * (1.0f - wx);
            float w01 = (1.0f - wy) * wx;
            float w10 = wy * (1.0f - wx);
            float w11 = wy * wx;

            if (MASKED) {
                const float vx0 = ((unsigned)x0       < IMG_W) ? 1.0f : 0.0f;
                const float vx1 = ((unsigned)(x0 + 1) < IMG_W) ? 1.0f : 0.0f;
                const float vy0 = ((unsigned)y0       < IMG_H) ? 1.0f : 0.0f;
                const float vy1 = ((unsigned)(y0 + 1) < IMG_H) ? 1.0f : 0.0f;
                w00 *= vy0 * vx0;
                w01 *= vy0 * vx1;
                w10 *= vy1 * vx0;
                w11 *= vy1 * vx1;
            }

            const int lr = y0 - ys0;
            const int lc = x0 - xs0a;
            const float* __restrict__ p = &tile[lr * LCOLS + lc];
            const float v00 = p[0];
            const float v01 = p[1];
            const float v10 = p[LCOLS];
            const float v11 = p[LCOLS + 1];

            o[k] = v00 * w00 + v01 * w01 + v10 * w10 + v11 * w11;
        }
        *reinterpret_cast<float4*>(&dst[y * IMG_W + X0 + col4]) =
            make_float4(o[0], o[1], o[2], o[3]);
    }
}

__global__ __launch_bounds__(256) void rot_kernel(const float* __restrict__ in,
                                                  float* __restrict__ out) {
    const float a = 0.96592582628906831f;  // cos(15 deg)
    const float b = 0.25881904510252074f;  // sin(15 deg)

    __shared__ float tile[LDS_FLOATS];

    const int blk = blockIdx.x;
    const int tx = blk & 7;
    const int ty = (blk >> 3) & 7;
    const int bc = blk >> 6;     // plane 0..95
    const int X0 = tx * TS;
    const int Y0 = ty * TS;

    // Footprint origin — same fp formula shape as the per-pixel math so that
    // rounding keeps every tap inside [0,LROWS)x[0,LCOLS).
    const float fx_lo = (float)X0 - 256.0f;
    const float fy_lo = (float)Y0 - 256.0f;
    const float fy_hi = (float)(Y0 + 63) - 256.0f;
    const float xs_min = a * fx_lo + (-b * fy_hi + 256.0f);
    const float ys_min = b * fx_lo + ( a * fy_lo + 256.0f);
    const int xs0  = (int)floorf(xs_min);
    const int ys0  = (int)floorf(ys_min);
    const int xs0a = xs0 & ~3;   // 16B-aligned column origin (rounds toward -inf)

    const int t = threadIdx.x;
    const int wave = t >> 6;
    const int plane_base = bc * (IMG_H * IMG_W);
    const int total = NPLANES * IMG_H * IMG_W;

    // ---- Stage footprint HBM -> LDS directly (7 x global_load_lds dwordx4).
    //      LDS dest is wave-uniform base + lane*16 (linear layout, stride 84
    //      floats = 21 aligned 16B groups per row). Global addr is per-lane,
    //      buffer-clamped (out-of-image cells hold finite don't-care values).
#pragma unroll
    for (int it = 0; it < NGROUPS / 256; ++it) {
        const int g = it * 256 + t;           // 16B-group id, 0..1791
        const int r = g / 21;                 // footprint row
        const int c4 = (g - r * 21) << 2;     // col offset (multiple of 4)
        int gidx = plane_base + (ys0 + r) * IMG_W + xs0a + c4;
        gidx = min(max(gidx, 0), total - 4);
        __builtin_amdgcn_global_load_lds(
            (gfloat*)(in + gidx),
            (sfloat*)&tile[(it * 256 + (wave << 6)) * 4],
            16, 0, 0);
    }
    __syncthreads();

    float* __restrict__ dst = out + (size_t)bc * (IMG_H * IMG_W);

    // Block-uniform interior test: if the whole padded footprint lies inside
    // the image, every tap is valid -> skip border masks (scalar branch).
    const bool interior = (xs0a >= 0) && (xs0a + LCOLS <= IMG_W) &&
                          (ys0 >= 0) && (ys0 + LROWS <= IMG_H);
    if (interior) {
        compute_tile<false>(tile, dst, X0, Y0, xs0a, ys0, t, a, b);
    } else {
        compute_tile<true>(tile, dst, X0, Y0, xs0a, ys0, t, a, b);
    }
}

extern "C" void kernel_launch(void* const* d_in, const int* in_sizes, int n_in,
                              void* d_out, int out_size, void* d_ws, size_t ws_size,
                              hipStream_t stream) {
    const float* in = (const float*)d_in[0];
    float* out = (float*)d_out;

    const int grid = NPLANES * (IMG_H / TS) * (IMG_W / TS);  // 6144
    rot_kernel<<<grid, 256, 0, stream>>>(in, out);
}

// Round 5
// 174.042 us; speedup vs baseline: 1.4456x; 1.0046x over previous
//
#include <hip/hip_runtime.h>

// Rotation of (32,3,512,512) fp32 by 15 degrees, bilinear, border=0.
// LDS-tiled, async-staged, occupancy-tuned: each 256-thread block computes a
// 64(wide)x32(tall) output tile. Rotated source footprint (50 rows x 76-col
// stride, 16B-aligned origin) staged via global_load_lds width=16 directly
// HBM->LDS (4 instructions/thread), then bilinear taps read from LDS.
// LDS = 16.4 KB/block -> 8 blocks/CU -> 32 waves/CU (100% occupancy).
// Out-of-image cells are address-clamped finite garbage, masked exactly to
// zero by validity weights, matching the reference's  vals * (w * valid).

#define IMG_H 512
#define IMG_W 512
#define NPLANES 96            // B*C
#define TSX 64                // tile width
#define TSY 32                // tile height
#define LROWS 50              // footprint rows  (63*sin + 31*cos + margins)
#define LCOLS 76              // footprint col stride (63*cos+31*sin+1+3 align -> 73, pad 76)
#define GPR 19                // 16B groups per row (76/4)
#define NGROUPS_PAD 1024      // ceil(50*19=950 -> 4*256)
#define LDS_FLOATS (NGROUPS_PAD * 4)   // 4096 floats = 16384 B

typedef __attribute__((address_space(1))) const float gfloat;
typedef __attribute__((address_space(3))) float sfloat;

template <bool MASKED>
__device__ __forceinline__ void compute_tile(const float* __restrict__ tile,
                                             float* __restrict__ dst,
                                             int X0, int Y0, int xs0a, int ys0,
                                             int t, float a, float b) {
    const int col4 = (t & 15) << 2;
    const int row_base = t >> 4;
#pragma unroll
    for (int rr = 0; rr < 2; ++rr) {
        const int y = Y0 + row_base + (rr << 4);
        const float fy = (float)y - 256.0f;
        const float bxs = -b * fy + 256.0f;
        const float bys =  a * fy + 256.0f;

        float o[4];
#pragma unroll
        for (int k = 0; k < 4; ++k) {
            const int x = X0 + col4 + k;
            const float fx = (float)x - 256.0f;
            const float xs = a * fx + bxs;
            const float ys = b * fx + bys;

            const float x0f = floorf(xs);
            const float y0f = floorf(ys);
            const float wx = xs - x0f;
            const float wy = ys - y0f;
            const int x0 = (int)x0f;
            const int y0 = (int)y0f;

            float w00 = (1.0f - wy) * (1.0f - wx);
            float w01 = (1.0f - wy) * wx;
            float w10 = wy * (1.0f - wx);
            float w11 = wy * wx;

            if (MASKED) {
                const float vx0 = ((unsigned)x0       < IMG_W) ? 1.0f : 0.0f;
                const float vx1 = ((unsigned)(x0 + 1) < IMG_W) ? 1.0f : 0.0f;
                const float vy0 = ((unsigned)y0       < IMG_H) ? 1.0f : 0.0f;
                const float vy1 = ((unsigned)(y0 + 1) < IMG_H) ? 1.0f : 0.0f;
                w00 *= vy0 * vx0;
                w01 *= vy0 * vx1;
                w10 *= vy1 * vx0;
                w11 *= vy1 * vx1;
            }

            const int lr = y0 - ys0;
            const int lc = x0 - xs0a;
            const float* __restrict__ p = &tile[lr * LCOLS + lc];
            const float v00 = p[0];
            const float v01 = p[1];
            const float v10 = p[LCOLS];
            const float v11 = p[LCOLS + 1];

            o[k] = v00 * w00 + v01 * w01 + v10 * w10 + v11 * w11;
        }
        *reinterpret_cast<float4*>(&dst[y * IMG_W + X0 + col4]) =
            make_float4(o[0], o[1], o[2], o[3]);
    }
}

__global__ __launch_bounds__(256, 8) void rot_kernel(const float* __restrict__ in,
                                                     float* __restrict__ out) {
    const float a = 0.96592582628906831f;  // cos(15 deg)
    const float b = 0.25881904510252074f;  // sin(15 deg)

    __shared__ float tile[LDS_FLOATS];

    const int blk = blockIdx.x;
    const int tx = blk & 7;            // 8 tiles across (64 wide)
    const int ty = (blk >> 3) & 15;    // 16 tiles down (32 tall)
    const int bc = blk >> 7;           // plane 0..95
    const int X0 = tx * TSX;
    const int Y0 = ty * TSY;

    // Footprint origin — identical fp op shapes to the per-pixel math, so
    // monotone fp rounding bounds every tap inside [0,LROWS)x[0,LCOLS).
    const float fx_lo = (float)X0 - 256.0f;
    const float fy_lo = (float)Y0 - 256.0f;
    const float fy_hi = (float)(Y0 + (TSY - 1)) - 256.0f;
    const float xs_min = a * fx_lo + (-b * fy_hi + 256.0f);
    const float ys_min = b * fx_lo + ( a * fy_lo + 256.0f);
    const int xs0  = (int)floorf(xs_min);
    const int ys0  = (int)floorf(ys_min);
    const int xs0a = xs0 & ~3;         // 16B-aligned column origin

    const int t = threadIdx.x;
    const int wave = t >> 6;
    const int plane_base = bc * (IMG_H * IMG_W);
    const int total = NPLANES * IMG_H * IMG_W;

    // ---- Stage footprint HBM -> LDS (4 x global_load_lds dwordx4 / thread).
    //      LDS dest: wave-uniform base + lane*16, linear row-major [50][76].
    //      Global addr per-lane, clamped into the tensor (garbage cells are
    //      masked by zero weights).
#pragma unroll
    for (int it = 0; it < NGROUPS_PAD / 256; ++it) {
        const int g = it * 256 + t;           // 16B-group id
        const int r = g / GPR;                // footprint row (pad rows clamp)
        const int c4 = (g - r * GPR) << 2;
        int gidx = plane_base + (ys0 + r) * IMG_W + xs0a + c4;
        gidx = min(max(gidx, 0), total - 4);
        __builtin_amdgcn_global_load_lds(
            (gfloat*)(in + gidx),
            (sfloat*)&tile[(it * 256 + (wave << 6)) * 4],
            16, 0, 0);
    }
    __syncthreads();

    float* __restrict__ dst = out + (size_t)bc * (IMG_H * IMG_W);

    const bool interior = (xs0a >= 0) && (xs0a + LCOLS <= IMG_W) &&
                          (ys0 >= 0) && (ys0 + LROWS <= IMG_H);
    if (interior) {
        compute_tile<false>(tile, dst, X0, Y0, xs0a, ys0, t, a, b);
    } else {
        compute_tile<true>(tile, dst, X0, Y0, xs0a, ys0, t, a, b);
    }
}

extern "C" void kernel_launch(void* const* d_in, const int* in_sizes, int n_in,
                              void* d_out, int out_size, void* d_ws, size_t ws_size,
                              hipStream_t stream) {
    const float* in = (const float*)d_in[0];
    float* out = (float*)d_out;

    // 96 planes * 8 * 16 tiles = 12288 blocks
    const int grid = NPLANES * (IMG_W / TSX) * (IMG_H / TSY);
    rot_kernel<<<grid, 256, 0, stream>>>(in, out);
}